// Round 1
// baseline (481.537 us; speedup 1.0000x reference)
//
#include <hip/hip_runtime.h>
#include <math.h>

#define D 65536
#define NT 256
#define NG 256
#define NL 1024
#define NS 1280          // NG + NL
#define CT 32            // column tiles in kA
#define TILE_W 2048      // columns per tile (32 per lane)
#define RG 40            // row groups (32 rows each)
#define KC_SPLIT 8       // blocks per teacher row

typedef float vfloat4 __attribute__((ext_vector_type(4)));

// ws layout (floats):
// [0, D)                          : Sxs (column sums of u_s)
// [D, +NS*CT*2)                   : stats float2 [row][tile]  (m, Z partials)
// [.., +NT*KC_SPLIT*4)            : teacher tuples float4 (m, Z, A, Dg)
// [.., +RG*D)                     : per-rowgroup column-sum partials (non-atomic path)

__device__ __forceinline__ float max4(vfloat4 v) {
    return fmaxf(fmaxf(v.x, v.y), fmaxf(v.z, v.w));
}
__device__ __forceinline__ vfloat4 vmax4(vfloat4 a, vfloat4 b) {
    vfloat4 r;
    r.x = fmaxf(a.x, b.x); r.y = fmaxf(a.y, b.y);
    r.z = fmaxf(a.z, b.z); r.w = fmaxf(a.w, b.w);
    return r;
}
__device__ __forceinline__ vfloat4 exp4(vfloat4 v) {
    vfloat4 r;
    r.x = __expf(v.x); r.y = __expf(v.y);
    r.z = __expf(v.z); r.w = __expf(v.w);
    return r;
}

__global__ __launch_bounds__(256) void kA(const float* __restrict__ sg,
                                          const float* __restrict__ sl,
                                          const float* __restrict__ tempS,
                                          float* __restrict__ Sxs,
                                          float* __restrict__ partial,
                                          float2* __restrict__ stats,
                                          int use_atomic) {
    const int tid  = threadIdx.x;
    const int lane = tid & 63;
    const int w    = tid >> 6;           // wave 0..3
    const int ct   = blockIdx.x;         // 0..31
    const int gy   = blockIdx.y;         // 0..39
    const int c0   = ct * TILE_W;
    const float invTs = 1.0f / tempS[0];
    // 32-row groups align with the 256-row global/local boundary (gy >= 8 -> local)
    const float* __restrict__ base =
        (gy >= 8) ? (sl + (size_t)(gy - 8) * 32 * D) : (sg + (size_t)gy * 32 * D);

    __shared__ float lds_sx[4][TILE_W];  // 32 KB

    vfloat4 sx[8];
    #pragma unroll
    for (int j = 0; j < 8; ++j) sx[j] = (vfloat4)0.0f;

    // wave w handles rows {w, 4+w, ..., 28+w}; two-pass max->exp per row
    #pragma unroll 2
    for (int i = 0; i < 8; ++i) {
        const int r = i * 4 + w;         // wave-uniform row within group
        const vfloat4* __restrict__ p = (const vfloat4*)(base + (size_t)r * D + c0) + lane;
        vfloat4 x[8];
        #pragma unroll
        for (int j = 0; j < 8; ++j) x[j] = p[j * 64];   // 8 independent 16B loads
        #pragma unroll
        for (int j = 0; j < 8; ++j) { x[j] *= invTs; sx[j] += x[j]; }
        const vfloat4 mx = vmax4(vmax4(vmax4(x[0], x[1]), vmax4(x[2], x[3])),
                                 vmax4(vmax4(x[4], x[5]), vmax4(x[6], x[7])));
        float m = max4(mx);
        const vfloat4 e0 = exp4(x[0] - m), e1 = exp4(x[1] - m);
        const vfloat4 e2 = exp4(x[2] - m), e3 = exp4(x[3] - m);
        const vfloat4 e4 = exp4(x[4] - m), e5 = exp4(x[5] - m);
        const vfloat4 e6 = exp4(x[6] - m), e7 = exp4(x[7] - m);
        const vfloat4 es = ((e0 + e1) + (e2 + e3)) + ((e4 + e5) + (e6 + e7));
        float z = (es.x + es.y) + (es.z + es.w);
        // merge (m,z) across the 64 lanes of this row
        #pragma unroll
        for (int off = 32; off; off >>= 1) {
            const float m2 = __shfl_xor(m, off, 64);
            const float z2 = __shfl_xor(z, off, 64);
            const float mn = fmaxf(m, m2);
            z = z * __expf(m - mn) + z2 * __expf(m2 - mn);
            m = mn;
        }
        if (lane == 0)
            stats[(size_t)(gy * 32 + r) * CT + ct] = make_float2(m, z);
    }

    // combine per-wave column sums via LDS
    #pragma unroll
    for (int ch = 0; ch < 8; ++ch)
        ((vfloat4*)&lds_sx[w][ch * 256])[lane] = sx[ch];
    __syncthreads();

    #pragma unroll
    for (int k = 0; k < 2; ++k) {
        const int i4 = k * 256 + tid;        // float4 index within tile (512 total)
        vfloat4 v = ((vfloat4*)lds_sx[0])[i4] + ((vfloat4*)lds_sx[1])[i4]
                  + ((vfloat4*)lds_sx[2])[i4] + ((vfloat4*)lds_sx[3])[i4];
        if (use_atomic) {
            const int c = c0 + i4 * 4;
            atomicAdd(&Sxs[c + 0], v.x);
            atomicAdd(&Sxs[c + 1], v.y);
            atomicAdd(&Sxs[c + 2], v.z);
            atomicAdd(&Sxs[c + 3], v.w);
        } else {
            ((vfloat4*)(partial + (size_t)gy * D + c0))[i4] = v;
        }
    }
}

__global__ __launch_bounds__(256) void kB(const float* __restrict__ partial,
                                          float* __restrict__ Sxs) {
    const int i4 = blockIdx.x * 256 + threadIdx.x;   // float4 column index
    const vfloat4* __restrict__ p = (const vfloat4*)partial;
    vfloat4 s = (vfloat4)0.0f;
    #pragma unroll 8
    for (int g = 0; g < RG; ++g) s += p[(size_t)g * (D / 4) + i4];
    ((vfloat4*)Sxs)[i4] = s;
}

__global__ __launch_bounds__(256) void kC(const float* __restrict__ tch,
                                          const float* __restrict__ sg,
                                          const float* __restrict__ center,
                                          const float* __restrict__ Sxs,
                                          const float* __restrict__ tempS,
                                          const float* __restrict__ tempT,
                                          float4* __restrict__ tup) {
    const int t   = blockIdx.x >> 3;     // teacher row
    const int q   = blockIdx.x & 7;      // column slice
    const int tid = threadIdx.x;
    const float invTt = 1.0f / tempT[0];
    const float invTs = 1.0f / tempS[0];

    const vfloat4* __restrict__ xt = (const vfloat4*)(tch + (size_t)t * D);
    const vfloat4* __restrict__ xg = (const vfloat4*)(sg  + (size_t)t * D);
    const vfloat4* __restrict__ c4 = (const vfloat4*)center;
    const vfloat4* __restrict__ s4 = (const vfloat4*)Sxs;

    const int base = q * (D / 4 / KC_SPLIT);         // 2048 float4 per slice
    // two independent online chains (even/odd iterations)
    float m0 = -INFINITY, Z0 = 0.0f, A0 = 0.0f, G0 = 0.0f;
    float m1 = -INFINITY, Z1 = 0.0f, A1 = 0.0f, G1 = 0.0f;

    #pragma unroll
    for (int it = 0; it < (D / 4 / KC_SPLIT) / 256; it += 2) {
        const int ia = base + it * 256 + tid;
        const int ib = ia + 256;
        const vfloat4 xa = xt[ia], ga = xg[ia], ca = c4[ia], sa = s4[ia];
        const vfloat4 xb = xt[ib], gb = xg[ib], cb = c4[ib], sb = s4[ib];

        const vfloat4 ya = (xa - ca) * invTt;
        const float mna = fmaxf(m0, max4(ya));
        const float sca = __expf(m0 - mna);
        const vfloat4 fa = exp4(ya - mna);
        Z0 = Z0 * sca + ((fa.x + fa.y) + (fa.z + fa.w));
        A0 = A0 * sca + ((fa.x * sa.x + fa.y * sa.y) + (fa.z * sa.z + fa.w * sa.w));
        G0 = G0 * sca + ((fa.x * ga.x + fa.y * ga.y) + (fa.z * ga.z + fa.w * ga.w));
        m0 = mna;

        const vfloat4 yb = (xb - cb) * invTt;
        const float mnb = fmaxf(m1, max4(yb));
        const float scb = __expf(m1 - mnb);
        const vfloat4 fb = exp4(yb - mnb);
        Z1 = Z1 * scb + ((fb.x + fb.y) + (fb.z + fb.w));
        A1 = A1 * scb + ((fb.x * sb.x + fb.y * sb.y) + (fb.z * sb.z + fb.w * sb.w));
        G1 = G1 * scb + ((fb.x * gb.x + fb.y * gb.y) + (fb.z * gb.z + fb.w * gb.w));
        m1 = mnb;
    }
    // merge the two chains; Dg is linear in invTs -> apply once here
    float m = fmaxf(m0, m1);
    {
        const float s1 = __expf(m0 - m);
        const float s2 = __expf(m1 - m);
        Z0 = Z0 * s1 + Z1 * s2;
        A0 = A0 * s1 + A1 * s2;
        G0 = (G0 * s1 + G1 * s2) * invTs;
    }
    float Z = Z0, A = A0, Dg = G0;
    // butterfly tuple merge across the wave
    #pragma unroll
    for (int off = 32; off; off >>= 1) {
        const float m2 = __shfl_xor(m,  off, 64);
        const float Z2 = __shfl_xor(Z,  off, 64);
        const float A2 = __shfl_xor(A,  off, 64);
        const float G2 = __shfl_xor(Dg, off, 64);
        const float mn = fmaxf(m, m2);
        const float s1 = __expf(m  - mn);
        const float s2 = __expf(m2 - mn);
        Z  = Z  * s1 + Z2 * s2;
        A  = A  * s1 + A2 * s2;
        Dg = Dg * s1 + G2 * s2;
        m  = mn;
    }
    __shared__ float4 lds[4];
    const int w = tid >> 6, lane = tid & 63;
    if (lane == 0) lds[w] = make_float4(m, Z, A, Dg);
    __syncthreads();
    if (tid == 0) {
        float4 r = lds[0];
        for (int k = 1; k < 4; ++k) {
            const float4 p = lds[k];
            const float mn = fmaxf(r.x, p.x);
            const float s1 = __expf(r.x - mn);
            const float s2 = __expf(p.x - mn);
            r = make_float4(mn, r.y*s1 + p.y*s2, r.z*s1 + p.z*s2, r.w*s1 + p.w*s2);
        }
        tup[blockIdx.x] = r;
    }
}

__device__ __forceinline__ float2 merge2(float2 a, float2 b) {
    const float mn = fmaxf(a.x, b.x);
    return make_float2(mn, a.y * __expf(a.x - mn) + b.y * __expf(b.x - mn));
}

__global__ __launch_bounds__(256) void kD(const float2* __restrict__ stats,
                                          const float4* __restrict__ tup,
                                          float* __restrict__ out) {
    const int tid = threadIdx.x;
    float accC = 0.0f, accCg = 0.0f;
    for (int r = tid; r < NS; r += 256) {
        // CT=32 float2 per row = 16 float4
        const float4* sp = (const float4*)(stats + (size_t)r * CT);
        float4 v[16];
        #pragma unroll
        for (int k = 0; k < 16; ++k) v[k] = sp[k];   // independent loads
        float2 p[16];
        #pragma unroll
        for (int k = 0; k < 16; ++k)
            p[k] = merge2(make_float2(v[k].x, v[k].y), make_float2(v[k].z, v[k].w));
        #pragma unroll
        for (int step = 8; step; step >>= 1)
            #pragma unroll
            for (int k = 0; k < step; ++k) p[k] = merge2(p[k], p[k + step]);
        const float l = p[0].x + logf(p[0].y);
        accC += l;
        if (r < NG) accCg += l;
    }
    float termS = 0.0f;
    if (tid < NT) {
        float4 r = tup[KC_SPLIT * tid];
        for (int k = 1; k < KC_SPLIT; ++k) {
            const float4 pp = tup[KC_SPLIT * tid + k];
            const float mn = fmaxf(r.x, pp.x);
            const float s1 = __expf(r.x - mn);
            const float s2 = __expf(pp.x - mn);
            r = make_float4(mn, r.y*s1 + pp.y*s2, r.z*s1 + pp.z*s2, r.w*s1 + pp.w*s2);
        }
        termS = (r.z - r.w) / r.y;   // (A - Dg)/Z
    }
    // block reduce the three sums
    #pragma unroll
    for (int off = 32; off; off >>= 1) {
        accC  += __shfl_xor(accC,  off, 64);
        accCg += __shfl_xor(accCg, off, 64);
        termS += __shfl_xor(termS, off, 64);
    }
    __shared__ float l1[4], l2[4], l3[4];
    const int w = tid >> 6, lane = tid & 63;
    if (lane == 0) { l1[w] = accC; l2[w] = accCg; l3[w] = termS; }
    __syncthreads();
    if (tid == 0) {
        float C = 0.0f, Cg = 0.0f, S = 0.0f;
        for (int k = 0; k < 4; ++k) { C += l1[k]; Cg += l2[k]; S += l3[k]; }
        // total = 256*C - C_g - sum_t (A_t - Dg_t)/Z_t ; n_loss_terms = 256*1280-256
        out[0] = (256.0f * C - Cg - S) * (1.0f / 327424.0f);
    }
}

extern "C" void kernel_launch(void* const* d_in, const int* in_sizes, int n_in,
                              void* d_out, int out_size, void* d_ws, size_t ws_size,
                              hipStream_t stream) {
    const float* sg     = (const float*)d_in[0];   // out_student_global [256, D]
    const float* sl     = (const float*)d_in[1];   // out_student_local  [1024, D]
    const float* tch    = (const float*)d_in[2];   // out_teacher        [256, D]
    const float* center = (const float*)d_in[3];   // [1, D]
    const float* tempS  = (const float*)d_in[4];
    const float* tempT  = (const float*)d_in[5];
    // d_in[6] = cent_rate_m (unused by the reference output)

    float* ws = (float*)d_ws;
    float*  Sxs     = ws;                                         // D floats
    float2* stats   = (float2*)(ws + D);                          // NS*CT float2
    float4* tup     = (float4*)(ws + D + NS * CT * 2);            // NT*KC_SPLIT float4
    float*  partial = ws + D + NS * CT * 2 + NT * KC_SPLIT * 4;   // RG*D floats

    const size_t needed = (size_t)(D + NS * CT * 2 + NT * KC_SPLIT * 4 + RG * D) * sizeof(float);
    const int use_atomic = (ws_size < needed) ? 1 : 0;

    if (use_atomic)
        hipMemsetAsync(Sxs, 0, D * sizeof(float), stream);
    kA<<<dim3(CT, RG), 256, 0, stream>>>(sg, sl, tempS, Sxs, partial, stats, use_atomic);
    if (!use_atomic)
        kB<<<D / 1024, 256, 0, stream>>>(partial, Sxs);
    kC<<<NT * KC_SPLIT, 256, 0, stream>>>(tch, sg, center, Sxs, tempS, tempT, tup);
    kD<<<1, 256, 0, stream>>>(stats, tup, (float*)d_out);
}